// Round 1
// baseline (713.552 us; speedup 1.0000x reference)
//
#include <hip/hip_runtime.h>
#include <cstdint>

#define CCH 512
#define HW  4096
#define WDIM 64
#define NBATCH 8

// ---------------------------------------------------------------------------
// K1: f[b,o,p] = sum_c W[o,c] * X[b,c,p]   (M=512, N=4096, K=512 per batch)
// 128x128 tile, BK=16, 256 threads, 8x8 microtile (split 4+4 fragments).
// ---------------------------------------------------------------------------
__global__ __launch_bounds__(256, 2) void conv1x1_k(
    const float* __restrict__ X, const float* __restrict__ Wm,
    float* __restrict__ F) {
  const int bz = blockIdx.z;
  const float* Xb = X + (size_t)bz * CCH * HW;
  float* Fb = F + (size_t)bz * CCH * HW;
  const int n0 = blockIdx.x * 128;
  const int m0 = blockIdx.y * 128;

  __shared__ float As[16][128];  // As[k][m] = W[m0+m][k0+k]
  __shared__ float Bs[16][128];  // Bs[k][n] = X[k0+k][n0+n]

  const int tid = threadIdx.x;
  const int tx = tid & 15;   // 0..15 -> n fragment
  const int ty = tid >> 4;   // 0..15 -> m fragment

  float acc[8][8];
#pragma unroll
  for (int i = 0; i < 8; ++i)
#pragma unroll
    for (int j = 0; j < 8; ++j) acc[i][j] = 0.f;

  // global-load index maps
  const int arow = tid >> 1;         // 0..127 (m within tile)
  const int acol = (tid & 1) * 8;    // 0 or 8 (k within tile)
  const int brow = tid >> 4;         // 0..15  (k within tile)
  const int bcol = (tid & 15) * 8;   // 0..120 (n within tile)

  for (int k0 = 0; k0 < CCH; k0 += 16) {
    const float* aptr = &Wm[(size_t)(m0 + arow) * CCH + k0 + acol];
    float4 a0 = *(const float4*)(aptr);
    float4 a1 = *(const float4*)(aptr + 4);
    const float* bptr = &Xb[(size_t)(k0 + brow) * HW + n0 + bcol];
    float4 b0 = *(const float4*)(bptr);
    float4 b1 = *(const float4*)(bptr + 4);

    __syncthreads();  // previous iter finished reading LDS

    // transposed store of A
    As[acol + 0][arow] = a0.x;
    As[acol + 1][arow] = a0.y;
    As[acol + 2][arow] = a0.z;
    As[acol + 3][arow] = a0.w;
    As[acol + 4][arow] = a1.x;
    As[acol + 5][arow] = a1.y;
    As[acol + 6][arow] = a1.z;
    As[acol + 7][arow] = a1.w;
    *(float4*)&Bs[brow][bcol] = b0;
    *(float4*)&Bs[brow][bcol + 4] = b1;

    __syncthreads();

#pragma unroll
    for (int k = 0; k < 16; ++k) {
      float a[8], bb[8];
      float4 t;
      t = *(const float4*)&As[k][ty * 4];       a[0]=t.x; a[1]=t.y; a[2]=t.z; a[3]=t.w;
      t = *(const float4*)&As[k][64 + ty * 4];  a[4]=t.x; a[5]=t.y; a[6]=t.z; a[7]=t.w;
      t = *(const float4*)&Bs[k][tx * 4];       bb[0]=t.x; bb[1]=t.y; bb[2]=t.z; bb[3]=t.w;
      t = *(const float4*)&Bs[k][64 + tx * 4];  bb[4]=t.x; bb[5]=t.y; bb[6]=t.z; bb[7]=t.w;
#pragma unroll
      for (int ii = 0; ii < 8; ++ii)
#pragma unroll
        for (int jj = 0; jj < 8; ++jj)
          acc[ii][jj] = fmaf(a[ii], bb[jj], acc[ii][jj]);
    }
  }

#pragma unroll
  for (int ih = 0; ih < 2; ++ih) {
#pragma unroll
    for (int r = 0; r < 4; ++r) {
      const int m = m0 + ih * 64 + ty * 4 + r;
      float* dst = &Fb[(size_t)m * HW + n0];
      float4 v;
      v.x = acc[ih * 4 + r][0]; v.y = acc[ih * 4 + r][1];
      v.z = acc[ih * 4 + r][2]; v.w = acc[ih * 4 + r][3];
      *(float4*)&dst[tx * 4] = v;
      v.x = acc[ih * 4 + r][4]; v.y = acc[ih * 4 + r][5];
      v.z = acc[ih * 4 + r][6]; v.w = acc[ih * 4 + r][7];
      *(float4*)&dst[64 + tx * 4] = v;
    }
  }
}

// ---------------------------------------------------------------------------
// K2: S[b,c,i,j] = sum_h F[b,c,h,i] * F[b,c,h,j]   (64x64x64 per (b,c))
// one wave per block, 8x8 microtile (split 4+4), K staged 16 rows at a time.
// ---------------------------------------------------------------------------
__global__ __launch_bounds__(64, 4) void gram_k(
    const float* __restrict__ F, float* __restrict__ S) {
  const size_t base = ((size_t)blockIdx.y * CCH + blockIdx.x) * HW;
  const float* Fc = F + base;
  float* Sc = S + base;

  __shared__ float Fs[16][64];

  const int lane = threadIdx.x;
  const int tx = lane & 7;    // j fragment
  const int ty = lane >> 3;   // i fragment

  float acc[8][8];
#pragma unroll
  for (int i = 0; i < 8; ++i)
#pragma unroll
    for (int j = 0; j < 8; ++j) acc[i][j] = 0.f;

  const int lrow = lane >> 2;        // 0..15
  const int lcol = (lane & 3) * 16;  // 0,16,32,48

  for (int h0 = 0; h0 < 64; h0 += 16) {
    const float* src = &Fc[(size_t)(h0 + lrow) * WDIM + lcol];
    float4 v0 = *(const float4*)(src + 0);
    float4 v1 = *(const float4*)(src + 4);
    float4 v2 = *(const float4*)(src + 8);
    float4 v3 = *(const float4*)(src + 12);
    __syncthreads();
    *(float4*)&Fs[lrow][lcol + 0]  = v0;
    *(float4*)&Fs[lrow][lcol + 4]  = v1;
    *(float4*)&Fs[lrow][lcol + 8]  = v2;
    *(float4*)&Fs[lrow][lcol + 12] = v3;
    __syncthreads();

#pragma unroll
    for (int k = 0; k < 16; ++k) {
      float a[8], bb[8];
      float4 t;
      t = *(const float4*)&Fs[k][ty * 4];       a[0]=t.x; a[1]=t.y; a[2]=t.z; a[3]=t.w;
      t = *(const float4*)&Fs[k][32 + ty * 4];  a[4]=t.x; a[5]=t.y; a[6]=t.z; a[7]=t.w;
      t = *(const float4*)&Fs[k][tx * 4];       bb[0]=t.x; bb[1]=t.y; bb[2]=t.z; bb[3]=t.w;
      t = *(const float4*)&Fs[k][32 + tx * 4];  bb[4]=t.x; bb[5]=t.y; bb[6]=t.z; bb[7]=t.w;
#pragma unroll
      for (int ii = 0; ii < 8; ++ii)
#pragma unroll
        for (int jj = 0; jj < 8; ++jj)
          acc[ii][jj] = fmaf(a[ii], bb[jj], acc[ii][jj]);
    }
  }

#pragma unroll
  for (int ih = 0; ih < 2; ++ih) {
#pragma unroll
    for (int r = 0; r < 4; ++r) {
      const int i = ih * 32 + ty * 4 + r;
      float4 v;
      v.x = acc[ih * 4 + r][0]; v.y = acc[ih * 4 + r][1];
      v.z = acc[ih * 4 + r][2]; v.w = acc[ih * 4 + r][3];
      *(float4*)&Sc[(size_t)i * WDIM + tx * 4] = v;
      v.x = acc[ih * 4 + r][4]; v.y = acc[ih * 4 + r][5];
      v.z = acc[ih * 4 + r][6]; v.w = acc[ih * 4 + r][7];
      *(float4*)&Sc[(size_t)i * WDIM + 32 + tx * 4] = v;
    }
  }
}

// ---------------------------------------------------------------------------
// K3: per (b,i,j): softmax over c for both branches (two-pass online),
// hadamard, then out = Fo*Fs*(ho*hs)^2. Block = (b,i), 256 thr = 64 j x 4
// c-groups; group partials merged via LDS.
// ---------------------------------------------------------------------------
__global__ __launch_bounds__(256, 2) void softmax_fuse_k(
    const float* __restrict__ So, const float* __restrict__ Ss,
    const float* __restrict__ Fo, const float* __restrict__ Fs,
    float* __restrict__ Out) {
  const int i = blockIdx.x;   // 0..63
  const int b = blockIdx.y;
  const int j = threadIdx.x & 63;
  const int g = threadIdx.x >> 6;  // 0..3

  const size_t base = ((size_t)b * CCH) * HW + (size_t)i * WDIM + j;

  float mo = -1e30f, lo = 0.f, ms = -1e30f, ls = 0.f;
#pragma unroll 4
  for (int cc = 0; cc < 128; ++cc) {
    const int c = g * 128 + cc;
    const size_t idx = base + (size_t)c * HW;
    const float xo = So[idx];
    const float xs = Ss[idx];
    if (xo <= mo) {
      lo += __expf(xo - mo);
    } else {
      lo = lo * __expf(mo - xo) + 1.f;
      mo = xo;
    }
    if (xs <= ms) {
      ls += __expf(xs - ms);
    } else {
      ls = ls * __expf(ms - xs) + 1.f;
      ms = xs;
    }
  }

  __shared__ float sm[2][4][64];
  __shared__ float sl[2][4][64];
  sm[0][g][j] = mo; sl[0][g][j] = lo;
  sm[1][g][j] = ms; sl[1][g][j] = ls;
  __syncthreads();

  float Mo = -1e30f, Ms = -1e30f;
#pragma unroll
  for (int t = 0; t < 4; ++t) {
    Mo = fmaxf(Mo, sm[0][t][j]);
    Ms = fmaxf(Ms, sm[1][t][j]);
  }
  float Lo = 0.f, Ls = 0.f;
#pragma unroll
  for (int t = 0; t < 4; ++t) {
    Lo += sl[0][t][j] * __expf(sm[0][t][j] - Mo);
    Ls += sl[1][t][j] * __expf(sm[1][t][j] - Ms);
  }
  const float invLo = 1.f / Lo;
  const float invLs = 1.f / Ls;

#pragma unroll 4
  for (int cc = 0; cc < 128; ++cc) {
    const int c = g * 128 + cc;
    const size_t idx = base + (size_t)c * HW;
    const float ho = __expf(So[idx] - Mo) * invLo;
    const float hs = __expf(Ss[idx] - Ms) * invLs;
    float h2 = ho * hs;
    h2 *= h2;
    Out[idx] = Fo[idx] * Fs[idx] * h2;
  }
}

// ---------------------------------------------------------------------------
extern "C" void kernel_launch(void* const* d_in, const int* in_sizes, int n_in,
                              void* d_out, int out_size, void* d_ws, size_t ws_size,
                              hipStream_t stream) {
  const float* opt = (const float*)d_in[0];
  const float* sar = (const float*)d_in[1];
  const float* Wo  = (const float*)d_in[2];
  const float* Wsr = (const float*)d_in[3];
  float* out = (float*)d_out;

  const size_t perBatch = (size_t)CCH * HW;              // elems per batch per buffer
  const size_t perBatchBytes = perBatch * 4ull * 4ull;   // 4 fp32 buffers
  int bc = (int)(ws_size / perBatchBytes);
  if (bc < 1) bc = 1;
  if (bc > NBATCH) bc = NBATCH;

  float* f_o = (float*)d_ws;
  float* f_s = f_o + (size_t)bc * perBatch;
  float* S_o = f_s + (size_t)bc * perBatch;
  float* S_s = S_o + (size_t)bc * perBatch;

  for (int b0 = 0; b0 < NBATCH; b0 += bc) {
    const int nb = (NBATCH - b0 < bc) ? (NBATCH - b0) : bc;

    dim3 g1(HW / 128, CCH / 128, nb);   // 32 x 4 x nb
    hipLaunchKernelGGL(conv1x1_k, g1, dim3(256), 0, stream,
                       opt + (size_t)b0 * perBatch, Wo, f_o);
    hipLaunchKernelGGL(conv1x1_k, g1, dim3(256), 0, stream,
                       sar + (size_t)b0 * perBatch, Wsr, f_s);

    dim3 g2(CCH, nb);
    hipLaunchKernelGGL(gram_k, g2, dim3(64), 0, stream, f_o, S_o);
    hipLaunchKernelGGL(gram_k, g2, dim3(64), 0, stream, f_s, S_s);

    dim3 g3(WDIM, nb);
    hipLaunchKernelGGL(softmax_fuse_k, g3, dim3(256), 0, stream,
                       S_o, S_s, f_o, f_s, out + (size_t)b0 * perBatch);
  }
}

// Round 2
// 535.873 us; speedup vs baseline: 1.3316x; 1.3316x over previous
//
#include <hip/hip_runtime.h>
#include <cstdint>

#define CCH 512
#define HW  4096
#define WDIM 64
#define NBATCH 8
#define CHW ((size_t)CCH * HW)

typedef __attribute__((ext_vector_type(8))) short bf16x8;
typedef __attribute__((ext_vector_type(4))) float f32x4;

__device__ __forceinline__ unsigned short f2bf(float x) {
  unsigned u = __float_as_uint(x);
  unsigned r = (u + 0x7FFFu + ((u >> 16) & 1u)) >> 16;
  return (unsigned short)r;
}
__device__ __forceinline__ float bf2f(unsigned short h) {
  return __uint_as_float(((unsigned)h) << 16);
}

__device__ __forceinline__ void gl_lds16(const void* g, void* l) {
  __builtin_amdgcn_global_load_lds(
      (const __attribute__((address_space(1))) void*)g,
      (__attribute__((address_space(3))) void*)l, 16, 0, 0);
}

// ---------------------------------------------------------------------------
// P0: split W (fp32 [o][c]) -> bf16 hi/lo, same layout. Both branches (y).
// Whl layout: [br][hi: 262144][lo: 262144] ushort.
// ---------------------------------------------------------------------------
__global__ __launch_bounds__(256) void wsplit_k(
    const float* __restrict__ Wo, const float* __restrict__ Wsr,
    unsigned short* __restrict__ Whl) {
  const int br = blockIdx.y;
  const float* W = br ? Wsr : Wo;
  const int i = blockIdx.x * 256 + threadIdx.x;  // 0..262143
  const float x = W[i];
  const unsigned short h = f2bf(x);
  unsigned short* dst = Whl + (size_t)br * 524288;
  dst[i] = h;
  dst[262144 + i] = f2bf(x - bf2f(h));
}

// ---------------------------------------------------------------------------
// P1: transpose + split X: fp32 [c][p] -> bf16 Xt[p][c] hi & lo.
// z = bl*2 + br over the chunk.
// ---------------------------------------------------------------------------
__global__ __launch_bounds__(256) void splitT_k(
    const float* __restrict__ opt, const float* __restrict__ sar,
    unsigned short* __restrict__ Xth, unsigned short* __restrict__ Xtl,
    int b0) {
  const int z = blockIdx.z;
  const int br = z & 1, bl = z >> 1;
  const float* X = (br ? sar : opt) + (size_t)(b0 + bl) * CHW;
  unsigned short* oh = Xth + (size_t)z * CHW;
  unsigned short* ol = Xtl + (size_t)z * CHW;
  const int p0 = blockIdx.x * 64, c0 = blockIdx.y * 64;

  __shared__ float ts[64][65];
  const int tid = threadIdx.x;

  const int pl = (tid & 15) * 4;
#pragma unroll
  for (int rr = 0; rr < 4; ++rr) {
    const int cl = rr * 16 + (tid >> 4);
    float4 v = *(const float4*)&X[(size_t)(c0 + cl) * HW + p0 + pl];
    ts[cl][pl + 0] = v.x;
    ts[cl][pl + 1] = v.y;
    ts[cl][pl + 2] = v.z;
    ts[cl][pl + 3] = v.w;
  }
  __syncthreads();

  const int prow = tid >> 2;         // 0..63
  const int cch = (tid & 3) * 16;    // 0,16,32,48
  unsigned short hb[16], lb[16];
#pragma unroll
  for (int k = 0; k < 16; ++k) {
    const float x = ts[cch + k][prow];
    const unsigned short h = f2bf(x);
    hb[k] = h;
    lb[k] = f2bf(x - bf2f(h));
  }
  const size_t ob = (size_t)(p0 + prow) * CCH + c0 + cch;
  *(uint4*)&oh[ob] = *(uint4*)&hb[0];
  *(uint4*)&oh[ob + 8] = *(uint4*)&hb[8];
  *(uint4*)&ol[ob] = *(uint4*)&lb[0];
  *(uint4*)&ol[ob + 8] = *(uint4*)&lb[8];
}

// ---------------------------------------------------------------------------
// K1: MFMA GEMM  F[o][p] = sum_c W[o][c] * Xt[p][c]   (TN, both K-contig)
// 128x128 tile, BK=32, split-bf16 3-product. z = bl*2+br.
// ---------------------------------------------------------------------------
__global__ __launch_bounds__(256, 2) void mfma_conv_k(
    const unsigned short* __restrict__ Whl,
    const unsigned short* __restrict__ Xth,
    const unsigned short* __restrict__ Xtl,
    float* __restrict__ F) {
  const int z = blockIdx.z;
  const int br = z & 1;
  const unsigned short* Ah_g = Whl + (size_t)br * 524288;
  const unsigned short* Al_g = Ah_g + 262144;
  const unsigned short* Bh_g = Xth + (size_t)z * CHW;
  const unsigned short* Bl_g = Xtl + (size_t)z * CHW;
  const int n0 = blockIdx.x * 128, m0 = blockIdx.y * 128;

  __shared__ unsigned short Ahs[128 * 32];
  __shared__ unsigned short Als[128 * 32];
  __shared__ unsigned short Bhs[128 * 32];
  __shared__ unsigned short Bls[128 * 32];

  const int tid = threadIdx.x;
  const int wave = tid >> 6, lane = tid & 63;
  const int wm = (wave >> 1) * 64, wn = (wave & 1) * 64;

  f32x4 acc[4][4] = {};

  const int rl = lane >> 2;        // staging: row within 16-row chunk
  const int kc = (lane & 3) * 8;   // staging: bf16 k-offset

  for (int k0 = 0; k0 < CCH; k0 += 32) {
    __syncthreads();
#pragma unroll
    for (int q = 0; q < 2; ++q) {
      const int rbase = wave * 32 + q * 16;
      const int r = rbase + rl;
      gl_lds16(Ah_g + (size_t)(m0 + r) * CCH + k0 + kc, &Ahs[rbase * 32]);
      gl_lds16(Al_g + (size_t)(m0 + r) * CCH + k0 + kc, &Als[rbase * 32]);
      gl_lds16(Bh_g + (size_t)(n0 + r) * CCH + k0 + kc, &Bhs[rbase * 32]);
      gl_lds16(Bl_g + (size_t)(n0 + r) * CCH + k0 + kc, &Bls[rbase * 32]);
    }
    __syncthreads();

    const int fr = lane & 15, kh = (lane >> 4) * 8;
    bf16x8 ah[4], al[4], bh[4], bl[4];
#pragma unroll
    for (int i = 0; i < 4; ++i) {
      ah[i] = *(const bf16x8*)&Ahs[(wm + i * 16 + fr) * 32 + kh];
      al[i] = *(const bf16x8*)&Als[(wm + i * 16 + fr) * 32 + kh];
      bh[i] = *(const bf16x8*)&Bhs[(wn + i * 16 + fr) * 32 + kh];
      bl[i] = *(const bf16x8*)&Bls[(wn + i * 16 + fr) * 32 + kh];
    }
#pragma unroll
    for (int i = 0; i < 4; ++i)
#pragma unroll
      for (int j = 0; j < 4; ++j) {
        acc[i][j] = __builtin_amdgcn_mfma_f32_16x16x32_bf16(ah[i], bh[j], acc[i][j], 0, 0, 0);
        acc[i][j] = __builtin_amdgcn_mfma_f32_16x16x32_bf16(ah[i], bl[j], acc[i][j], 0, 0, 0);
        acc[i][j] = __builtin_amdgcn_mfma_f32_16x16x32_bf16(al[i], bh[j], acc[i][j], 0, 0, 0);
      }
  }

  float* Fb = F + (size_t)z * CHW;
  const int col = lane & 15, rq = (lane >> 4) * 4;
#pragma unroll
  for (int i = 0; i < 4; ++i)
#pragma unroll
    for (int j = 0; j < 4; ++j) {
      const int n = n0 + wn + j * 16 + col;
#pragma unroll
      for (int r = 0; r < 4; ++r) {
        const int m = m0 + wm + i * 16 + rq + r;
        Fb[(size_t)m * HW + n] = acc[i][j][r];
      }
    }
}

// ---------------------------------------------------------------------------
// K2: S[z,c,i,j] = sum_h F[z,c,h,i] * F[z,c,h,j]  (fp32, one wave per (z,c))
// ---------------------------------------------------------------------------
__global__ __launch_bounds__(64, 4) void gram_k(
    const float* __restrict__ F, float* __restrict__ S) {
  const size_t base = ((size_t)blockIdx.y * CCH + blockIdx.x) * HW;
  const float* Fc = F + base;
  float* Sc = S + base;

  __shared__ float Fs[16][64];

  const int lane = threadIdx.x;
  const int tx = lane & 7;
  const int ty = lane >> 3;

  float acc[8][8];
#pragma unroll
  for (int i = 0; i < 8; ++i)
#pragma unroll
    for (int j = 0; j < 8; ++j) acc[i][j] = 0.f;

  const int lrow = lane >> 2;
  const int lcol = (lane & 3) * 16;

  for (int h0 = 0; h0 < 64; h0 += 16) {
    const float* src = &Fc[(size_t)(h0 + lrow) * WDIM + lcol];
    float4 v0 = *(const float4*)(src + 0);
    float4 v1 = *(const float4*)(src + 4);
    float4 v2 = *(const float4*)(src + 8);
    float4 v3 = *(const float4*)(src + 12);
    __syncthreads();
    *(float4*)&Fs[lrow][lcol + 0] = v0;
    *(float4*)&Fs[lrow][lcol + 4] = v1;
    *(float4*)&Fs[lrow][lcol + 8] = v2;
    *(float4*)&Fs[lrow][lcol + 12] = v3;
    __syncthreads();

#pragma unroll
    for (int k = 0; k < 16; ++k) {
      float a[8], bb[8];
      float4 t;
      t = *(const float4*)&Fs[k][ty * 4];      a[0]=t.x; a[1]=t.y; a[2]=t.z; a[3]=t.w;
      t = *(const float4*)&Fs[k][32 + ty * 4]; a[4]=t.x; a[5]=t.y; a[6]=t.z; a[7]=t.w;
      t = *(const float4*)&Fs[k][tx * 4];      bb[0]=t.x; bb[1]=t.y; bb[2]=t.z; bb[3]=t.w;
      t = *(const float4*)&Fs[k][32 + tx * 4]; bb[4]=t.x; bb[5]=t.y; bb[6]=t.z; bb[7]=t.w;
#pragma unroll
      for (int ii = 0; ii < 8; ++ii)
#pragma unroll
        for (int jj = 0; jj < 8; ++jj)
          acc[ii][jj] = fmaf(a[ii], bb[jj], acc[ii][jj]);
    }
  }

#pragma unroll
  for (int ih = 0; ih < 2; ++ih) {
#pragma unroll
    for (int r = 0; r < 4; ++r) {
      const int i = ih * 32 + ty * 4 + r;
      float4 v;
      v.x = acc[ih * 4 + r][0]; v.y = acc[ih * 4 + r][1];
      v.z = acc[ih * 4 + r][2]; v.w = acc[ih * 4 + r][3];
      *(float4*)&Sc[(size_t)i * WDIM + tx * 4] = v;
      v.x = acc[ih * 4 + r][4]; v.y = acc[ih * 4 + r][5];
      v.z = acc[ih * 4 + r][6]; v.w = acc[ih * 4 + r][7];
      *(float4*)&Sc[(size_t)i * WDIM + 32 + tx * 4] = v;
    }
  }
}

// ---------------------------------------------------------------------------
// K3: softmax over c (both branches) + hadamard + output.
// S/F buffers interleaved per-bl: [bl*2+br][c][h][w].
// ---------------------------------------------------------------------------
__global__ __launch_bounds__(256, 2) void softmax_fuse_k(
    const float* __restrict__ S, const float* __restrict__ Fbuf,
    float* __restrict__ Out) {
  const int i = blockIdx.x;
  const int b = blockIdx.y;
  const int j = threadIdx.x & 63;
  const int g = threadIdx.x >> 6;

  const size_t bO = (size_t)b * 2 * CHW + (size_t)i * WDIM + j;
  const size_t bS = bO + CHW;

  float mo = -1e30f, lo = 0.f, ms = -1e30f, ls = 0.f;
#pragma unroll 4
  for (int cc = 0; cc < 128; ++cc) {
    const int c = g * 128 + cc;
    const size_t off = (size_t)c * HW;
    const float xo = S[bO + off];
    const float xs = S[bS + off];
    if (xo <= mo) {
      lo += __expf(xo - mo);
    } else {
      lo = lo * __expf(mo - xo) + 1.f;
      mo = xo;
    }
    if (xs <= ms) {
      ls += __expf(xs - ms);
    } else {
      ls = ls * __expf(ms - xs) + 1.f;
      ms = xs;
    }
  }

  __shared__ float sm[2][4][64];
  __shared__ float sl[2][4][64];
  sm[0][g][j] = mo; sl[0][g][j] = lo;
  sm[1][g][j] = ms; sl[1][g][j] = ls;
  __syncthreads();

  float Mo = -1e30f, Ms = -1e30f;
#pragma unroll
  for (int t = 0; t < 4; ++t) {
    Mo = fmaxf(Mo, sm[0][t][j]);
    Ms = fmaxf(Ms, sm[1][t][j]);
  }
  float Lo = 0.f, Ls = 0.f;
#pragma unroll
  for (int t = 0; t < 4; ++t) {
    Lo += sl[0][t][j] * __expf(sm[0][t][j] - Mo);
    Ls += sl[1][t][j] * __expf(sm[1][t][j] - Ms);
  }
  const float invLo = 1.f / Lo;
  const float invLs = 1.f / Ls;

#pragma unroll 4
  for (int cc = 0; cc < 128; ++cc) {
    const int c = g * 128 + cc;
    const size_t off = (size_t)c * HW;
    const float ho = __expf(S[bO + off] - Mo) * invLo;
    const float hs = __expf(S[bS + off] - Ms) * invLs;
    float h2 = ho * hs;
    h2 *= h2;
    Out[(size_t)b * CHW + off + (size_t)i * WDIM + j] =
        Fbuf[bO + off] * Fbuf[bS + off] * h2;
  }
}

// ---------------------------------------------------------------------------
extern "C" void kernel_launch(void* const* d_in, const int* in_sizes, int n_in,
                              void* d_out, int out_size, void* d_ws, size_t ws_size,
                              hipStream_t stream) {
  const float* opt = (const float*)d_in[0];
  const float* sar = (const float*)d_in[1];
  const float* Wo  = (const float*)d_in[2];
  const float* Wsr = (const float*)d_in[3];
  float* out = (float*)d_out;

  // workspace layout
  unsigned short* Whl = (unsigned short*)d_ws;          // 2 MB
  const size_t whlElems = 2u * 2u * 262144u;
  const size_t perBl = 2 * CHW;                         // elems per bl per buffer
  const size_t perBlBytes = perBl * (2 + 2 + 4 + 4);    // Xth,Xtl ushort; F,S float
  int bc = (int)((ws_size - whlElems * 2) / perBlBytes);
  if (bc < 1) bc = 1;
  if (bc > NBATCH) bc = NBATCH;

  unsigned short* Xth = Whl + whlElems;
  unsigned short* Xtl = Xth + (size_t)bc * perBl;
  float* Fbuf = (float*)(Xtl + (size_t)bc * perBl);
  float* Sbuf = Fbuf + (size_t)bc * perBl;

  hipLaunchKernelGGL(wsplit_k, dim3(1024, 2), dim3(256), 0, stream, Wo, Wsr, Whl);

  for (int b0 = 0; b0 < NBATCH; b0 += bc) {
    const int nb = (NBATCH - b0 < bc) ? (NBATCH - b0) : bc;

    hipLaunchKernelGGL(splitT_k, dim3(64, 8, nb * 2), dim3(256), 0, stream,
                       opt, sar, Xth, Xtl, b0);

    hipLaunchKernelGGL(mfma_conv_k, dim3(32, 4, nb * 2), dim3(256), 0, stream,
                       Whl, Xth, Xtl, Fbuf);

    hipLaunchKernelGGL(gram_k, dim3(CCH, nb * 2), dim3(64), 0, stream,
                       Fbuf, Sbuf);

    hipLaunchKernelGGL(softmax_fuse_k, dim3(WDIM, nb), dim3(256), 0, stream,
                       Sbuf, Fbuf, out + (size_t)b0 * CHW);
  }
}

// Round 3
// 427.142 us; speedup vs baseline: 1.6705x; 1.2546x over previous
//
#include <hip/hip_runtime.h>
#include <cstdint>

#define CCH 512
#define HW  4096
#define WDIM 64
#define NBATCH 8
#define CHW ((size_t)CCH * HW)

typedef __attribute__((ext_vector_type(8))) short bf16x8;
typedef __attribute__((ext_vector_type(4))) float f32x4;

__device__ __forceinline__ unsigned short f2bf(float x) {
  unsigned u = __float_as_uint(x);
  unsigned r = (u + 0x7FFFu + ((u >> 16) & 1u)) >> 16;
  return (unsigned short)r;
}
__device__ __forceinline__ float bf2f(unsigned short h) {
  return __uint_as_float(((unsigned)h) << 16);
}

__device__ __forceinline__ void gl_lds16(const void* g, void* l) {
  __builtin_amdgcn_global_load_lds(
      (const __attribute__((address_space(1))) void*)g,
      (__attribute__((address_space(3))) void*)l, 16, 0, 0);
}

// ---------------------------------------------------------------------------
// P0: split W (fp32 [o][c]) -> bf16 hi/lo. Whl: [br][hi|lo] ushort.
// ---------------------------------------------------------------------------
__global__ __launch_bounds__(256) void wsplit_k(
    const float* __restrict__ Wo, const float* __restrict__ Wsr,
    unsigned short* __restrict__ Whl) {
  const int br = blockIdx.y;
  const float* W = br ? Wsr : Wo;
  const int i = blockIdx.x * 256 + threadIdx.x;
  const float x = W[i];
  const unsigned short h = f2bf(x);
  unsigned short* dst = Whl + (size_t)br * 524288;
  dst[i] = h;
  dst[262144 + i] = f2bf(x - bf2f(h));
}

// ---------------------------------------------------------------------------
// P1: transpose + split X: fp32 [c][p] -> bf16 Xt[p][c] hi & lo.
// ---------------------------------------------------------------------------
__global__ __launch_bounds__(256) void splitT_k(
    const float* __restrict__ opt, const float* __restrict__ sar,
    unsigned short* __restrict__ Xth, unsigned short* __restrict__ Xtl,
    int b0) {
  const int z = blockIdx.z;
  const int br = z & 1, bl = z >> 1;
  const float* X = (br ? sar : opt) + (size_t)(b0 + bl) * CHW;
  unsigned short* oh = Xth + (size_t)z * CHW;
  unsigned short* ol = Xtl + (size_t)z * CHW;
  const int p0 = blockIdx.x * 64, c0 = blockIdx.y * 64;

  __shared__ float ts[64][65];
  const int tid = threadIdx.x;

  const int pl = (tid & 15) * 4;
#pragma unroll
  for (int rr = 0; rr < 4; ++rr) {
    const int cl = rr * 16 + (tid >> 4);
    float4 v = *(const float4*)&X[(size_t)(c0 + cl) * HW + p0 + pl];
    ts[cl][pl + 0] = v.x;
    ts[cl][pl + 1] = v.y;
    ts[cl][pl + 2] = v.z;
    ts[cl][pl + 3] = v.w;
  }
  __syncthreads();

  const int prow = tid >> 2;
  const int cch = (tid & 3) * 16;
  unsigned short hb[16], lb[16];
#pragma unroll
  for (int k = 0; k < 16; ++k) {
    const float x = ts[cch + k][prow];
    const unsigned short h = f2bf(x);
    hb[k] = h;
    lb[k] = f2bf(x - bf2f(h));
  }
  const size_t ob = (size_t)(p0 + prow) * CCH + c0 + cch;
  *(uint4*)&oh[ob] = *(uint4*)&hb[0];
  *(uint4*)&oh[ob + 8] = *(uint4*)&hb[8];
  *(uint4*)&ol[ob] = *(uint4*)&lb[0];
  *(uint4*)&ol[ob + 8] = *(uint4*)&lb[8];
}

// ---------------------------------------------------------------------------
// K1: MFMA GEMM  F[o][p] = sum_c W[o][c] * Xt[p][c]  (split-bf16 3-product)
// ---------------------------------------------------------------------------
__global__ __launch_bounds__(256, 2) void mfma_conv_k(
    const unsigned short* __restrict__ Whl,
    const unsigned short* __restrict__ Xth,
    const unsigned short* __restrict__ Xtl,
    float* __restrict__ F) {
  const int z = blockIdx.z;
  const int br = z & 1;
  const unsigned short* Ah_g = Whl + (size_t)br * 524288;
  const unsigned short* Al_g = Ah_g + 262144;
  const unsigned short* Bh_g = Xth + (size_t)z * CHW;
  const unsigned short* Bl_g = Xtl + (size_t)z * CHW;
  const int n0 = blockIdx.x * 128, m0 = blockIdx.y * 128;

  __shared__ unsigned short Ahs[128 * 32];
  __shared__ unsigned short Als[128 * 32];
  __shared__ unsigned short Bhs[128 * 32];
  __shared__ unsigned short Bls[128 * 32];

  const int tid = threadIdx.x;
  const int wave = tid >> 6, lane = tid & 63;
  const int wm = (wave >> 1) * 64, wn = (wave & 1) * 64;

  f32x4 acc[4][4] = {};

  const int rl = lane >> 2;
  const int kc = (lane & 3) * 8;

  for (int k0 = 0; k0 < CCH; k0 += 32) {
    __syncthreads();
#pragma unroll
    for (int q = 0; q < 2; ++q) {
      const int rbase = wave * 32 + q * 16;
      const int r = rbase + rl;
      gl_lds16(Ah_g + (size_t)(m0 + r) * CCH + k0 + kc, &Ahs[rbase * 32]);
      gl_lds16(Al_g + (size_t)(m0 + r) * CCH + k0 + kc, &Als[rbase * 32]);
      gl_lds16(Bh_g + (size_t)(n0 + r) * CCH + k0 + kc, &Bhs[rbase * 32]);
      gl_lds16(Bl_g + (size_t)(n0 + r) * CCH + k0 + kc, &Bls[rbase * 32]);
    }
    __syncthreads();

    const int fr = lane & 15, kh = (lane >> 4) * 8;
    bf16x8 ah[4], al[4], bh[4], bl[4];
#pragma unroll
    for (int i = 0; i < 4; ++i) {
      ah[i] = *(const bf16x8*)&Ahs[(wm + i * 16 + fr) * 32 + kh];
      al[i] = *(const bf16x8*)&Als[(wm + i * 16 + fr) * 32 + kh];
      bh[i] = *(const bf16x8*)&Bhs[(wn + i * 16 + fr) * 32 + kh];
      bl[i] = *(const bf16x8*)&Bls[(wn + i * 16 + fr) * 32 + kh];
    }
#pragma unroll
    for (int i = 0; i < 4; ++i)
#pragma unroll
      for (int j = 0; j < 4; ++j) {
        acc[i][j] = __builtin_amdgcn_mfma_f32_16x16x32_bf16(ah[i], bh[j], acc[i][j], 0, 0, 0);
        acc[i][j] = __builtin_amdgcn_mfma_f32_16x16x32_bf16(ah[i], bl[j], acc[i][j], 0, 0, 0);
        acc[i][j] = __builtin_amdgcn_mfma_f32_16x16x32_bf16(al[i], bh[j], acc[i][j], 0, 0, 0);
      }
  }

  float* Fb = F + (size_t)z * CHW;
  const int col = lane & 15, rq = (lane >> 4) * 4;
#pragma unroll
  for (int i = 0; i < 4; ++i)
#pragma unroll
    for (int j = 0; j < 4; ++j) {
      const int n = n0 + wn + j * 16 + col;
#pragma unroll
      for (int r = 0; r < 4; ++r) {
        const int m = m0 + wm + i * 16 + rq + r;
        Fb[(size_t)m * HW + n] = acc[i][j][r];
      }
    }
}

// ---------------------------------------------------------------------------
// K2 v2: S = F^T F per (z,c) via split-bf16 MFMA. One channel per 256-thr
// block: fp32 LDS transpose (stride 68, conflict-free col reads) -> bf16
// hi/lo rows [w][h] (stride 72) -> 4 waves x 32x32 quadrant, K=64.
// ---------------------------------------------------------------------------
#define FT_S 72
__global__ __launch_bounds__(256, 4) void gram_k(
    const float* __restrict__ F, float* __restrict__ S) {
  const size_t base = ((size_t)blockIdx.y * CCH + blockIdx.x) * HW;
  const float* Fc = F + base;
  float* Sc = S + base;

  __shared__ float Fs[64][68];                 // 17408 B
  __shared__ unsigned short FtH[64 * FT_S];    // 9216 B
  __shared__ unsigned short FtL[64 * FT_S];    // 9216 B

  const int tid = threadIdx.x;

  // stage 64x64 fp32 rows into LDS (coalesced)
  {
    const int h = tid >> 2;
    const int w0 = (tid & 3) * 16;
    const float* src = &Fc[h * 64 + w0];
    float4 v0 = *(const float4*)(src + 0);
    float4 v1 = *(const float4*)(src + 4);
    float4 v2 = *(const float4*)(src + 8);
    float4 v3 = *(const float4*)(src + 12);
    *(float4*)&Fs[h][w0 + 0]  = v0;
    *(float4*)&Fs[h][w0 + 4]  = v1;
    *(float4*)&Fs[h][w0 + 8]  = v2;
    *(float4*)&Fs[h][w0 + 12] = v3;
  }
  __syncthreads();

  // transpose + split: thread (wave, l): w = l, h-chunk = wave*16
  {
    const int w = tid & 63;
    const int hc = (tid >> 6) * 16;
    unsigned short hb[16], lb[16];
#pragma unroll
    for (int k = 0; k < 16; ++k) {
      const float x = Fs[hc + k][w];
      const unsigned short h = f2bf(x);
      hb[k] = h;
      lb[k] = f2bf(x - bf2f(h));
    }
    unsigned short* dh = &FtH[w * FT_S + hc];
    unsigned short* dl = &FtL[w * FT_S + hc];
    *(uint4*)(dh + 0) = *(uint4*)&hb[0];
    *(uint4*)(dh + 8) = *(uint4*)&hb[8];
    *(uint4*)(dl + 0) = *(uint4*)&lb[0];
    *(uint4*)(dl + 8) = *(uint4*)&lb[8];
  }
  __syncthreads();

  const int wave = tid >> 6, lane = tid & 63;
  const int wm = (wave >> 1) * 32, wn = (wave & 1) * 32;
  const int fr = lane & 15, kq = (lane >> 4) * 8;

  f32x4 acc[2][2] = {};
#pragma unroll
  for (int kc = 0; kc < 2; ++kc) {
    bf16x8 ah[2], al[2], bh[2], bl[2];
#pragma unroll
    for (int i = 0; i < 2; ++i) {
      ah[i] = *(const bf16x8*)&FtH[(wm + i * 16 + fr) * FT_S + kc * 32 + kq];
      al[i] = *(const bf16x8*)&FtL[(wm + i * 16 + fr) * FT_S + kc * 32 + kq];
      bh[i] = *(const bf16x8*)&FtH[(wn + i * 16 + fr) * FT_S + kc * 32 + kq];
      bl[i] = *(const bf16x8*)&FtL[(wn + i * 16 + fr) * FT_S + kc * 32 + kq];
    }
#pragma unroll
    for (int i = 0; i < 2; ++i)
#pragma unroll
      for (int j = 0; j < 2; ++j) {
        acc[i][j] = __builtin_amdgcn_mfma_f32_16x16x32_bf16(ah[i], bh[j], acc[i][j], 0, 0, 0);
        acc[i][j] = __builtin_amdgcn_mfma_f32_16x16x32_bf16(ah[i], bl[j], acc[i][j], 0, 0, 0);
        acc[i][j] = __builtin_amdgcn_mfma_f32_16x16x32_bf16(al[i], bh[j], acc[i][j], 0, 0, 0);
      }
  }

  const int rq = (lane >> 4) * 4;
#pragma unroll
  for (int i = 0; i < 2; ++i)
#pragma unroll
    for (int j = 0; j < 2; ++j) {
      const int n = wn + j * 16 + fr;
#pragma unroll
      for (int r = 0; r < 4; ++r) {
        const int m = wm + i * 16 + rq + r;
        Sc[m * 64 + n] = acc[i][j][r];
      }
    }
}

// ---------------------------------------------------------------------------
// K3 v2: softmax over c (both branches) + hadamard + output.
// 512 thr: 32 c-groups x 16 j-lanes, float4 j-vectors, LDS merge.
// ---------------------------------------------------------------------------
__global__ __launch_bounds__(512, 4) void softmax_fuse_k(
    const float* __restrict__ S, const float* __restrict__ Fbuf,
    float* __restrict__ Out) {
  const int i = blockIdx.x;   // 0..63
  const int b = blockIdx.y;
  const int tid = threadIdx.x;
  const int jl = (tid & 15) * 4;
  const int g = tid >> 4;     // 0..31

  const size_t rowO = (size_t)(b * 2) * CHW + (size_t)i * WDIM;
  const size_t rowS = rowO + CHW;

  float mo[4], lo[4], ms[4], ls[4];
#pragma unroll
  for (int k = 0; k < 4; ++k) { mo[k] = -1e30f; lo[k] = 0.f; ms[k] = -1e30f; ls[k] = 0.f; }

#pragma unroll 4
  for (int cc = 0; cc < 16; ++cc) {
    const int c = g * 16 + cc;
    const size_t off = (size_t)c * HW + jl;
    float4 xo = *(const float4*)&S[rowO + off];
    float4 xs = *(const float4*)&S[rowS + off];
    float xov[4] = {xo.x, xo.y, xo.z, xo.w};
    float xsv[4] = {xs.x, xs.y, xs.z, xs.w};
#pragma unroll
    for (int k = 0; k < 4; ++k) {
      float nm = fmaxf(mo[k], xov[k]);
      lo[k] = lo[k] * __expf(mo[k] - nm) + __expf(xov[k] - nm);
      mo[k] = nm;
      nm = fmaxf(ms[k], xsv[k]);
      ls[k] = ls[k] * __expf(ms[k] - nm) + __expf(xsv[k] - nm);
      ms[k] = nm;
    }
  }

  __shared__ float sm[2][32][64];
  __shared__ float sl[2][32][64];
  __shared__ float Mf[2][64];
  __shared__ float Li[2][64];

  *(float4*)&sm[0][g][jl] = make_float4(mo[0], mo[1], mo[2], mo[3]);
  *(float4*)&sl[0][g][jl] = make_float4(lo[0], lo[1], lo[2], lo[3]);
  *(float4*)&sm[1][g][jl] = make_float4(ms[0], ms[1], ms[2], ms[3]);
  *(float4*)&sl[1][g][jl] = make_float4(ls[0], ls[1], ls[2], ls[3]);
  __syncthreads();

  if (tid < 128) {
    const int br = tid >> 6, j = tid & 63;
    float M = -1e30f;
#pragma unroll
    for (int t = 0; t < 32; ++t) M = fmaxf(M, sm[br][t][j]);
    float L = 0.f;
#pragma unroll
    for (int t = 0; t < 32; ++t) L += sl[br][t][j] * __expf(sm[br][t][j] - M);
    Mf[br][j] = M;
    Li[br][j] = 1.f / L;
  }
  __syncthreads();

  float4 Mo4 = *(const float4*)&Mf[0][jl];
  float4 iLo4 = *(const float4*)&Li[0][jl];
  float4 Ms4 = *(const float4*)&Mf[1][jl];
  float4 iLs4 = *(const float4*)&Li[1][jl];
  float Mov[4] = {Mo4.x, Mo4.y, Mo4.z, Mo4.w};
  float iLov[4] = {iLo4.x, iLo4.y, iLo4.z, iLo4.w};
  float Msv[4] = {Ms4.x, Ms4.y, Ms4.z, Ms4.w};
  float iLsv[4] = {iLs4.x, iLs4.y, iLs4.z, iLs4.w};

  const size_t outBase = (size_t)b * CHW + (size_t)i * WDIM + jl;

#pragma unroll 4
  for (int cc = 0; cc < 16; ++cc) {
    const int c = g * 16 + cc;
    const size_t off = (size_t)c * HW + jl;
    float4 xo = *(const float4*)&S[rowO + off];
    float4 xs = *(const float4*)&S[rowS + off];
    float4 fo = *(const float4*)&Fbuf[rowO + off];
    float4 fs = *(const float4*)&Fbuf[rowS + off];
    float xov[4] = {xo.x, xo.y, xo.z, xo.w};
    float xsv[4] = {xs.x, xs.y, xs.z, xs.w};
    float fov[4] = {fo.x, fo.y, fo.z, fo.w};
    float fsv[4] = {fs.x, fs.y, fs.z, fs.w};
    float ov[4];
#pragma unroll
    for (int k = 0; k < 4; ++k) {
      const float ho = __expf(xov[k] - Mov[k]) * iLov[k];
      const float hs = __expf(xsv[k] - Msv[k]) * iLsv[k];
      float h2 = ho * hs;
      h2 *= h2;
      ov[k] = fov[k] * fsv[k] * h2;
    }
    *(float4*)&Out[(size_t)c * HW + outBase - jl + jl] =
        make_float4(ov[0], ov[1], ov[2], ov[3]);
  }
}

// ---------------------------------------------------------------------------
extern "C" void kernel_launch(void* const* d_in, const int* in_sizes, int n_in,
                              void* d_out, int out_size, void* d_ws, size_t ws_size,
                              hipStream_t stream) {
  const float* opt = (const float*)d_in[0];
  const float* sar = (const float*)d_in[1];
  const float* Wo  = (const float*)d_in[2];
  const float* Wsr = (const float*)d_in[3];
  float* out = (float*)d_out;

  // workspace: Whl | Xth | Xtl | F ; S aliases [Xth,Xtl] (dead after conv)
  unsigned short* Whl = (unsigned short*)d_ws;
  const size_t whlElems = 2u * 2u * 262144u;     // 1M ushorts = 2 MB
  const size_t perBl = 2 * CHW;                  // elems per bl per buffer
  const size_t perBlBytes = perBl * 8;           // Xth(2)+Xtl(2)+F(4)
  int bc = (int)((ws_size - whlElems * 2) / perBlBytes);
  if (bc < 1) bc = 1;
  if (bc > NBATCH) bc = NBATCH;

  unsigned short* Xth = Whl + whlElems;
  unsigned short* Xtl = Xth + (size_t)bc * perBl;
  float* Fbuf = (float*)(Xtl + (size_t)bc * perBl);
  float* Sbuf = (float*)Xth;                     // alias

  hipLaunchKernelGGL(wsplit_k, dim3(1024, 2), dim3(256), 0, stream, Wo, Wsr, Whl);

  for (int b0 = 0; b0 < NBATCH; b0 += bc) {
    const int nb = (NBATCH - b0 < bc) ? (NBATCH - b0) : bc;

    hipLaunchKernelGGL(splitT_k, dim3(64, 8, nb * 2), dim3(256), 0, stream,
                       opt, sar, Xth, Xtl, b0);

    hipLaunchKernelGGL(mfma_conv_k, dim3(32, 4, nb * 2), dim3(256), 0, stream,
                       Whl, Xth, Xtl, Fbuf);

    hipLaunchKernelGGL(gram_k, dim3(CCH, nb * 2), dim3(256), 0, stream,
                       Fbuf, Sbuf);

    hipLaunchKernelGGL(softmax_fuse_k, dim3(WDIM, nb), dim3(512), 0, stream,
                       Sbuf, Fbuf, out + (size_t)b0 * CHW);
  }
}

// Round 4
// 419.474 us; speedup vs baseline: 1.7011x; 1.0183x over previous
//
#include <hip/hip_runtime.h>
#include <cstdint>

#define CCH 512
#define HW  4096
#define WDIM 64
#define NBATCH 8
#define CHW ((size_t)CCH * HW)

typedef __attribute__((ext_vector_type(8))) short bf16x8;
typedef __attribute__((ext_vector_type(4))) float f32x4;

__device__ __forceinline__ unsigned short f2bf(float x) {
  unsigned u = __float_as_uint(x);
  unsigned r = (u + 0x7FFFu + ((u >> 16) & 1u)) >> 16;
  return (unsigned short)r;
}
__device__ __forceinline__ float bf2f(unsigned short h) {
  return __uint_as_float(((unsigned)h) << 16);
}

__device__ __forceinline__ void gl_lds16(const void* g, void* l) {
  __builtin_amdgcn_global_load_lds(
      (const __attribute__((address_space(1))) void*)g,
      (__attribute__((address_space(3))) void*)l, 16, 0, 0);
}

// ---------------------------------------------------------------------------
// P0: split W (fp32 [o][c]) -> bf16 hi/lo. Whl: [br][hi|lo] ushort.
// ---------------------------------------------------------------------------
__global__ __launch_bounds__(256) void wsplit_k(
    const float* __restrict__ Wo, const float* __restrict__ Wsr,
    unsigned short* __restrict__ Whl) {
  const int br = blockIdx.y;
  const float* W = br ? Wsr : Wo;
  const int i = blockIdx.x * 256 + threadIdx.x;
  const float x = W[i];
  const unsigned short h = f2bf(x);
  unsigned short* dst = Whl + (size_t)br * 524288;
  dst[i] = h;
  dst[262144 + i] = f2bf(x - bf2f(h));
}

// ---------------------------------------------------------------------------
// P1: transpose + split X: fp32 [c][p] -> bf16 Xt[p][c] hi & lo.
// ---------------------------------------------------------------------------
__global__ __launch_bounds__(256) void splitT_k(
    const float* __restrict__ opt, const float* __restrict__ sar,
    unsigned short* __restrict__ Xth, unsigned short* __restrict__ Xtl,
    int b0) {
  const int z = blockIdx.z;
  const int br = z & 1, bl = z >> 1;
  const float* X = (br ? sar : opt) + (size_t)(b0 + bl) * CHW;
  unsigned short* oh = Xth + (size_t)z * CHW;
  unsigned short* ol = Xtl + (size_t)z * CHW;
  const int p0 = blockIdx.x * 64, c0 = blockIdx.y * 64;

  __shared__ float ts[64][65];
  const int tid = threadIdx.x;

  const int pl = (tid & 15) * 4;
#pragma unroll
  for (int rr = 0; rr < 4; ++rr) {
    const int cl = rr * 16 + (tid >> 4);
    float4 v = *(const float4*)&X[(size_t)(c0 + cl) * HW + p0 + pl];
    ts[cl][pl + 0] = v.x;
    ts[cl][pl + 1] = v.y;
    ts[cl][pl + 2] = v.z;
    ts[cl][pl + 3] = v.w;
  }
  __syncthreads();

  const int prow = tid >> 2;
  const int cch = (tid & 3) * 16;
  unsigned short hb[16], lb[16];
#pragma unroll
  for (int k = 0; k < 16; ++k) {
    const float x = ts[cch + k][prow];
    const unsigned short h = f2bf(x);
    hb[k] = h;
    lb[k] = f2bf(x - bf2f(h));
  }
  const size_t ob = (size_t)(p0 + prow) * CCH + c0 + cch;
  *(uint4*)&oh[ob] = *(uint4*)&hb[0];
  *(uint4*)&oh[ob + 8] = *(uint4*)&hb[8];
  *(uint4*)&ol[ob] = *(uint4*)&lb[0];
  *(uint4*)&ol[ob + 8] = *(uint4*)&lb[8];
}

// ---------------------------------------------------------------------------
// K1: MFMA GEMM  F[o][p] = sum_c W[o][c] * Xt[p][c]  (split-bf16 3-product)
// XOR-swizzled K-chunks in LDS: LDS(row, chunk p) = global chunk p ^
// ((row>>1)&3). Staging swizzles the SOURCE address (dest stays lane-linear
// per the global_load_lds constraint); fragment reads swizzle kh.
// 4 blocks/CU.
// ---------------------------------------------------------------------------
__global__ __launch_bounds__(256, 4) void mfma_conv_k(
    const unsigned short* __restrict__ Whl,
    const unsigned short* __restrict__ Xth,
    const unsigned short* __restrict__ Xtl,
    float* __restrict__ F) {
  const int z = blockIdx.z;
  const int br = z & 1;
  const unsigned short* Ah_g = Whl + (size_t)br * 524288;
  const unsigned short* Al_g = Ah_g + 262144;
  const unsigned short* Bh_g = Xth + (size_t)z * CHW;
  const unsigned short* Bl_g = Xtl + (size_t)z * CHW;
  const int n0 = blockIdx.x * 128, m0 = blockIdx.y * 128;

  __shared__ unsigned short Ahs[128 * 32];
  __shared__ unsigned short Als[128 * 32];
  __shared__ unsigned short Bhs[128 * 32];
  __shared__ unsigned short Bls[128 * 32];

  const int tid = threadIdx.x;
  const int wave = tid >> 6, lane = tid & 63;
  const int wm = (wave >> 1) * 64, wn = (wave & 1) * 64;

  f32x4 acc[4][4] = {};

  const int rl = lane >> 2;                               // staging row in chunk
  const int kc = (((lane & 3) ^ ((lane >> 3) & 3)) * 8);  // swizzled src chunk

  for (int k0 = 0; k0 < CCH; k0 += 32) {
    __syncthreads();
#pragma unroll
    for (int q = 0; q < 2; ++q) {
      const int rbase = wave * 32 + q * 16;
      const int r = rbase + rl;
      gl_lds16(Ah_g + (size_t)(m0 + r) * CCH + k0 + kc, &Ahs[rbase * 32]);
      gl_lds16(Al_g + (size_t)(m0 + r) * CCH + k0 + kc, &Als[rbase * 32]);
      gl_lds16(Bh_g + (size_t)(n0 + r) * CCH + k0 + kc, &Bhs[rbase * 32]);
      gl_lds16(Bl_g + (size_t)(n0 + r) * CCH + k0 + kc, &Bls[rbase * 32]);
    }
    __syncthreads();

    const int fr = lane & 15;
    const int kh = (((lane >> 4) ^ ((lane >> 1) & 3)) * 8);  // swizzled read
    bf16x8 ah[4], al[4], bh[4], bl[4];
#pragma unroll
    for (int i = 0; i < 4; ++i) {
      ah[i] = *(const bf16x8*)&Ahs[(wm + i * 16 + fr) * 32 + kh];
      al[i] = *(const bf16x8*)&Als[(wm + i * 16 + fr) * 32 + kh];
      bh[i] = *(const bf16x8*)&Bhs[(wn + i * 16 + fr) * 32 + kh];
      bl[i] = *(const bf16x8*)&Bls[(wn + i * 16 + fr) * 32 + kh];
    }
#pragma unroll
    for (int i = 0; i < 4; ++i)
#pragma unroll
      for (int j = 0; j < 4; ++j) {
        acc[i][j] = __builtin_amdgcn_mfma_f32_16x16x32_bf16(ah[i], bh[j], acc[i][j], 0, 0, 0);
        acc[i][j] = __builtin_amdgcn_mfma_f32_16x16x32_bf16(ah[i], bl[j], acc[i][j], 0, 0, 0);
        acc[i][j] = __builtin_amdgcn_mfma_f32_16x16x32_bf16(al[i], bh[j], acc[i][j], 0, 0, 0);
      }
  }

  float* Fb = F + (size_t)z * CHW;
  const int col = lane & 15, rq = (lane >> 4) * 4;
#pragma unroll
  for (int i = 0; i < 4; ++i)
#pragma unroll
    for (int j = 0; j < 4; ++j) {
      const int n = n0 + wn + j * 16 + col;
#pragma unroll
      for (int r = 0; r < 4; ++r) {
        const int m = m0 + wm + i * 16 + rq + r;
        Fb[(size_t)m * HW + n] = acc[i][j][r];
      }
    }
}

// ---------------------------------------------------------------------------
// K2: S = F^T F per (z,c) via split-bf16 MFMA; padded LDS (conflict-free).
// ---------------------------------------------------------------------------
#define FT_S 72
__global__ __launch_bounds__(256, 4) void gram_k(
    const float* __restrict__ F, float* __restrict__ S) {
  const size_t base = ((size_t)blockIdx.y * CCH + blockIdx.x) * HW;
  const float* Fc = F + base;
  float* Sc = S + base;

  __shared__ float Fs[64][68];
  __shared__ unsigned short FtH[64 * FT_S];
  __shared__ unsigned short FtL[64 * FT_S];

  const int tid = threadIdx.x;

  {
    const int h = tid >> 2;
    const int w0 = (tid & 3) * 16;
    const float* src = &Fc[h * 64 + w0];
    float4 v0 = *(const float4*)(src + 0);
    float4 v1 = *(const float4*)(src + 4);
    float4 v2 = *(const float4*)(src + 8);
    float4 v3 = *(const float4*)(src + 12);
    *(float4*)&Fs[h][w0 + 0]  = v0;
    *(float4*)&Fs[h][w0 + 4]  = v1;
    *(float4*)&Fs[h][w0 + 8]  = v2;
    *(float4*)&Fs[h][w0 + 12] = v3;
  }
  __syncthreads();

  {
    const int w = tid & 63;
    const int hc = (tid >> 6) * 16;
    unsigned short hb[16], lb[16];
#pragma unroll
    for (int k = 0; k < 16; ++k) {
      const float x = Fs[hc + k][w];
      const unsigned short h = f2bf(x);
      hb[k] = h;
      lb[k] = f2bf(x - bf2f(h));
    }
    unsigned short* dh = &FtH[w * FT_S + hc];
    unsigned short* dl = &FtL[w * FT_S + hc];
    *(uint4*)(dh + 0) = *(uint4*)&hb[0];
    *(uint4*)(dh + 8) = *(uint4*)&hb[8];
    *(uint4*)(dl + 0) = *(uint4*)&lb[0];
    *(uint4*)(dl + 8) = *(uint4*)&lb[8];
  }
  __syncthreads();

  const int wave = tid >> 6, lane = tid & 63;
  const int wm = (wave >> 1) * 32, wn = (wave & 1) * 32;
  const int fr = lane & 15, kq = (lane >> 4) * 8;

  f32x4 acc[2][2] = {};
#pragma unroll
  for (int kcc = 0; kcc < 2; ++kcc) {
    bf16x8 ah[2], al[2], bh[2], bl[2];
#pragma unroll
    for (int i = 0; i < 2; ++i) {
      ah[i] = *(const bf16x8*)&FtH[(wm + i * 16 + fr) * FT_S + kcc * 32 + kq];
      al[i] = *(const bf16x8*)&FtL[(wm + i * 16 + fr) * FT_S + kcc * 32 + kq];
      bh[i] = *(const bf16x8*)&FtH[(wn + i * 16 + fr) * FT_S + kcc * 32 + kq];
      bl[i] = *(const bf16x8*)&FtL[(wn + i * 16 + fr) * FT_S + kcc * 32 + kq];
    }
#pragma unroll
    for (int i = 0; i < 2; ++i)
#pragma unroll
      for (int j = 0; j < 2; ++j) {
        acc[i][j] = __builtin_amdgcn_mfma_f32_16x16x32_bf16(ah[i], bh[j], acc[i][j], 0, 0, 0);
        acc[i][j] = __builtin_amdgcn_mfma_f32_16x16x32_bf16(ah[i], bl[j], acc[i][j], 0, 0, 0);
        acc[i][j] = __builtin_amdgcn_mfma_f32_16x16x32_bf16(al[i], bh[j], acc[i][j], 0, 0, 0);
      }
  }

  const int rq = (lane >> 4) * 4;
#pragma unroll
  for (int i = 0; i < 2; ++i)
#pragma unroll
    for (int j = 0; j < 2; ++j) {
      const int n = wn + j * 16 + fr;
#pragma unroll
      for (int r = 0; r < 4; ++r) {
        const int m = wm + i * 16 + rq + r;
        Sc[m * 64 + n] = acc[i][j][r];
      }
    }
}

// ---------------------------------------------------------------------------
// K3 v3: softmax over c (both branches) + hadamard + output.
// 1024 thr/block = 64 c-groups x 16 j-lanes (x4 j). 2 blocks/CU.
// ---------------------------------------------------------------------------
__global__ __launch_bounds__(1024, 8) void softmax_fuse_k(
    const float* __restrict__ S, const float* __restrict__ Fbuf,
    float* __restrict__ Out) {
  const int i = blockIdx.x;   // 0..63
  const int b = blockIdx.y;
  const int tid = threadIdx.x;
  const int jl = (tid & 15) * 4;
  const int g = tid >> 4;     // 0..63 (8 c's each)

  const size_t rowO = (size_t)(b * 2) * CHW + (size_t)i * WDIM;
  const size_t rowS = rowO + CHW;

  float mo[4], lo[4], ms[4], ls[4];
#pragma unroll
  for (int k = 0; k < 4; ++k) { mo[k] = -1e30f; lo[k] = 0.f; ms[k] = -1e30f; ls[k] = 0.f; }

#pragma unroll
  for (int cc = 0; cc < 8; ++cc) {
    const int c = g * 8 + cc;
    const size_t off = (size_t)c * HW + jl;
    float4 xo = *(const float4*)&S[rowO + off];
    float4 xs = *(const float4*)&S[rowS + off];
    float xov[4] = {xo.x, xo.y, xo.z, xo.w};
    float xsv[4] = {xs.x, xs.y, xs.z, xs.w};
#pragma unroll
    for (int k = 0; k < 4; ++k) {
      float nm = fmaxf(mo[k], xov[k]);
      lo[k] = lo[k] * __expf(mo[k] - nm) + __expf(xov[k] - nm);
      mo[k] = nm;
      nm = fmaxf(ms[k], xsv[k]);
      ls[k] = ls[k] * __expf(ms[k] - nm) + __expf(xsv[k] - nm);
      ms[k] = nm;
    }
  }

  __shared__ float sm[2][64][64];
  __shared__ float sl[2][64][64];
  __shared__ float Mf[2][64];
  __shared__ float Li[2][64];

  *(float4*)&sm[0][g][jl] = make_float4(mo[0], mo[1], mo[2], mo[3]);
  *(float4*)&sl[0][g][jl] = make_float4(lo[0], lo[1], lo[2], lo[3]);
  *(float4*)&sm[1][g][jl] = make_float4(ms[0], ms[1], ms[2], ms[3]);
  *(float4*)&sl[1][g][jl] = make_float4(ls[0], ls[1], ls[2], ls[3]);
  __syncthreads();

  if (tid < 128) {
    const int br = tid >> 6, j = tid & 63;
    float M = -1e30f;
#pragma unroll 16
    for (int t = 0; t < 64; ++t) M = fmaxf(M, sm[br][t][j]);
    float L = 0.f;
#pragma unroll 16
    for (int t = 0; t < 64; ++t) L += sl[br][t][j] * __expf(sm[br][t][j] - M);
    Mf[br][j] = M;
    Li[br][j] = 1.f / L;
  }
  __syncthreads();

  float4 Mo4 = *(const float4*)&Mf[0][jl];
  float4 iLo4 = *(const float4*)&Li[0][jl];
  float4 Ms4 = *(const float4*)&Mf[1][jl];
  float4 iLs4 = *(const float4*)&Li[1][jl];
  float Mov[4] = {Mo4.x, Mo4.y, Mo4.z, Mo4.w};
  float iLov[4] = {iLo4.x, iLo4.y, iLo4.z, iLo4.w};
  float Msv[4] = {Ms4.x, Ms4.y, Ms4.z, Ms4.w};
  float iLsv[4] = {iLs4.x, iLs4.y, iLs4.z, iLs4.w};

#pragma unroll
  for (int cc = 0; cc < 8; ++cc) {
    const int c = g * 8 + cc;
    const size_t off = (size_t)c * HW + jl;
    float4 xo = *(const float4*)&S[rowO + off];
    float4 xs = *(const float4*)&S[rowS + off];
    float4 fo = *(const float4*)&Fbuf[rowO + off];
    float4 fs = *(const float4*)&Fbuf[rowS + off];
    float xov[4] = {xo.x, xo.y, xo.z, xo.w};
    float xsv[4] = {xs.x, xs.y, xs.z, xs.w};
    float fov[4] = {fo.x, fo.y, fo.z, fo.w};
    float fsv[4] = {fs.x, fs.y, fs.z, fs.w};
    float ov[4];
#pragma unroll
    for (int k = 0; k < 4; ++k) {
      const float ho = __expf(xov[k] - Mov[k]) * iLov[k];
      const float hs = __expf(xsv[k] - Msv[k]) * iLsv[k];
      float h2 = ho * hs;
      h2 *= h2;
      ov[k] = fov[k] * fsv[k] * h2;
    }
    *(float4*)&Out[(size_t)b * CHW + (size_t)c * HW + (size_t)i * WDIM + jl] =
        make_float4(ov[0], ov[1], ov[2], ov[3]);
  }
}

// ---------------------------------------------------------------------------
extern "C" void kernel_launch(void* const* d_in, const int* in_sizes, int n_in,
                              void* d_out, int out_size, void* d_ws, size_t ws_size,
                              hipStream_t stream) {
  const float* opt = (const float*)d_in[0];
  const float* sar = (const float*)d_in[1];
  const float* Wo  = (const float*)d_in[2];
  const float* Wsr = (const float*)d_in[3];
  float* out = (float*)d_out;

  // workspace: Whl | Xth | Xtl | F ; S aliases [Xth,Xtl] (dead after conv)
  unsigned short* Whl = (unsigned short*)d_ws;
  const size_t whlElems = 2u * 2u * 262144u;
  const size_t perBl = 2 * CHW;
  const size_t perBlBytes = perBl * 8;           // Xth(2)+Xtl(2)+F(4)
  int bc = (int)((ws_size - whlElems * 2) / perBlBytes);
  if (bc < 1) bc = 1;
  if (bc > NBATCH) bc = NBATCH;
  // even split across passes
  const int passes = (NBATCH + bc - 1) / bc;
  const int nbp = (NBATCH + passes - 1) / passes;

  unsigned short* Xth = Whl + whlElems;
  unsigned short* Xtl = Xth + (size_t)bc * perBl;
  float* Fbuf = (float*)(Xtl + (size_t)bc * perBl);
  float* Sbuf = (float*)Xth;                     // alias

  hipLaunchKernelGGL(wsplit_k, dim3(1024, 2), dim3(256), 0, stream, Wo, Wsr, Whl);

  for (int b0 = 0; b0 < NBATCH; b0 += nbp) {
    const int nb = (NBATCH - b0 < nbp) ? (NBATCH - b0) : nbp;

    hipLaunchKernelGGL(splitT_k, dim3(64, 8, nb * 2), dim3(256), 0, stream,
                       opt, sar, Xth, Xtl, b0);

    hipLaunchKernelGGL(mfma_conv_k, dim3(32, 4, nb * 2), dim3(256), 0, stream,
                       Whl, Xth, Xtl, Fbuf);

    hipLaunchKernelGGL(gram_k, dim3(CCH, nb * 2), dim3(256), 0, stream,
                       Fbuf, Sbuf);

    hipLaunchKernelGGL(softmax_fuse_k, dim3(WDIM, nb), dim3(1024), 0, stream,
                       Sbuf, Fbuf, out + (size_t)b0 * CHW);
  }
}

// Round 5
// 395.163 us; speedup vs baseline: 1.8057x; 1.0615x over previous
//
#include <hip/hip_runtime.h>
#include <cstdint>

#define CCH 512
#define HW  4096
#define WDIM 64
#define NBATCH 8
#define CHW ((size_t)CCH * HW)

typedef __attribute__((ext_vector_type(8))) short bf16x8;
typedef __attribute__((ext_vector_type(4))) float f32x4;

__device__ __forceinline__ unsigned short f2bf(float x) {
  unsigned u = __float_as_uint(x);
  unsigned r = (u + 0x7FFFu + ((u >> 16) & 1u)) >> 16;
  return (unsigned short)r;
}
__device__ __forceinline__ float bf2f(unsigned short h) {
  return __uint_as_float(((unsigned)h) << 16);
}

__device__ __forceinline__ void gl_lds16(const void* g, void* l) {
  __builtin_amdgcn_global_load_lds(
      (const __attribute__((address_space(1))) void*)g,
      (__attribute__((address_space(3))) void*)l, 16, 0, 0);
}

// ---------------------------------------------------------------------------
// P0: split W (fp32 [o][c]) -> bf16 hi/lo (RNE). Whl: [br][hi|lo] ushort.
// ---------------------------------------------------------------------------
__global__ __launch_bounds__(256) void wsplit_k(
    const float* __restrict__ Wo, const float* __restrict__ Wsr,
    unsigned short* __restrict__ Whl) {
  const int br = blockIdx.y;
  const float* W = br ? Wsr : Wo;
  const int i = blockIdx.x * 256 + threadIdx.x;
  const float x = W[i];
  const unsigned short h = f2bf(x);
  unsigned short* dst = Whl + (size_t)br * 524288;
  dst[i] = h;
  dst[262144 + i] = f2bf(x - bf2f(h));
}

// ---------------------------------------------------------------------------
// K1: MFMA GEMM  F[o][p] = sum_c W[o][c] * X[c][p]  (split-bf16 3-product).
// A (W hi/lo): precomputed bf16, K-contig, gl_lds16 staged with XOR-swizzled
//   k-chunks (round-4 scheme, conflict-free).
// B (X): staged as raw fp32 32x128 tile via gl_lds16 with per-row-group
//   column rotation 8*(row>>3) applied on the SOURCE address (dest is
//   lane-linear, per the DMA constraint). Fragments are built in-register
//   with a truncation hi/lo split (3 VALU/elem). Rotation makes the strided
//   b32 fragment reads conflict-free: bank = (fr + 8*quad + 16j) % 32.
// This replaces the separate splitT transpose kernel entirely.
// ---------------------------------------------------------------------------
__global__ __launch_bounds__(256, 4) void mfma_conv_k(
    const unsigned short* __restrict__ Whl,
    const float* __restrict__ opt, const float* __restrict__ sar,
    float* __restrict__ F, int b0) {
  const int z = blockIdx.z;
  const int br = z & 1, bl = z >> 1;
  const unsigned short* Ah_g = Whl + (size_t)br * 524288;
  const unsigned short* Al_g = Ah_g + 262144;
  const float* Xb = (br ? sar : opt) + (size_t)(b0 + bl) * CHW;
  const int n0 = blockIdx.x * 128, m0 = blockIdx.y * 128;

  __shared__ unsigned short Ahs[128 * 32];  // 8 KB
  __shared__ unsigned short Als[128 * 32];  // 8 KB
  __shared__ float Xs[32 * 128];            // 16 KB

  const int tid = threadIdx.x;
  const int wave = tid >> 6, lane = tid & 63;
  const int wm = (wave >> 1) * 64, wn = (wave & 1) * 64;

  f32x4 acc[4][4] = {};

  // A staging: row-in-chunk + swizzled source k-chunk (round-4 scheme)
  const int rl = lane >> 2;
  const int kcA = (((lane & 3) ^ ((lane >> 3) & 3)) * 8);

  // B staging: issue t covers rows t*8 + wave*2 + (lane>>5)
  const int brow_off = wave * 2 + (lane >> 5);  // 0..7
  const int bcol = (lane & 31) * 4;             // dest dword col 0..124

  const int fr = lane & 15;
  const int quad = lane >> 4;
  const int khA = ((quad ^ ((lane >> 1) & 3)) * 8);  // A read swizzle

  for (int k0 = 0; k0 < CCH; k0 += 32) {
    __syncthreads();
    // --- A: W hi/lo bf16 via DMA ---
#pragma unroll
    for (int q = 0; q < 2; ++q) {
      const int rbase = wave * 32 + q * 16;
      const int r = rbase + rl;
      gl_lds16(Ah_g + (size_t)(m0 + r) * CCH + k0 + kcA, &Ahs[rbase * 32]);
      gl_lds16(Al_g + (size_t)(m0 + r) * CCH + k0 + kcA, &Als[rbase * 32]);
    }
    // --- B: raw fp32 X tile, source-rotated by row group ---
#pragma unroll
    for (int t = 0; t < 4; ++t) {
      const int row = t * 8 + brow_off;
      const int srccol = (bcol + 128 - 8 * t) & 127;
      gl_lds16(&Xb[(size_t)(k0 + row) * HW + n0 + srccol],
               &Xs[t * 1024 + wave * 256]);
    }
    __syncthreads();

    // A fragments
    bf16x8 ah[4], al[4];
#pragma unroll
    for (int i = 0; i < 4; ++i) {
      ah[i] = *(const bf16x8*)&Ahs[(wm + i * 16 + fr) * 32 + khA];
      al[i] = *(const bf16x8*)&Als[(wm + i * 16 + fr) * 32 + khA];
    }

#pragma unroll
    for (int j = 0; j < 4; ++j) {
      // build B fragment pair for column n = wn + j*16 + fr
      const int colj = (wn + j * 16 + fr + 8 * quad) & 127;
      unsigned short hs[8], ls[8];
#pragma unroll
      for (int s = 0; s < 8; ++s) {
        const float x = Xs[(quad * 8 + s) * 128 + colj];
        const unsigned xu = __float_as_uint(x);
        const float hi = __uint_as_float(xu & 0xFFFF0000u);
        const float lof = x - hi;
        hs[s] = (unsigned short)(xu >> 16);
        ls[s] = (unsigned short)(__float_as_uint(lof) >> 16);
      }
      const bf16x8 bh = *(const bf16x8*)hs;
      const bf16x8 bl = *(const bf16x8*)ls;
#pragma unroll
      for (int i = 0; i < 4; ++i) {
        acc[i][j] = __builtin_amdgcn_mfma_f32_16x16x32_bf16(ah[i], bh, acc[i][j], 0, 0, 0);
        acc[i][j] = __builtin_amdgcn_mfma_f32_16x16x32_bf16(ah[i], bl, acc[i][j], 0, 0, 0);
        acc[i][j] = __builtin_amdgcn_mfma_f32_16x16x32_bf16(al[i], bh, acc[i][j], 0, 0, 0);
      }
    }
  }

  float* Fb = F + (size_t)z * CHW;
  const int col = lane & 15, rq = (lane >> 4) * 4;
#pragma unroll
  for (int i = 0; i < 4; ++i)
#pragma unroll
    for (int j = 0; j < 4; ++j) {
      const int n = n0 + wn + j * 16 + col;
#pragma unroll
      for (int r = 0; r < 4; ++r) {
        const int m = m0 + wm + i * 16 + rq + r;
        Fb[(size_t)m * HW + n] = acc[i][j][r];
      }
    }
}

// ---------------------------------------------------------------------------
// K2: S = F^T F per (z,c) via split-bf16 MFMA; padded LDS (conflict-free).
// ---------------------------------------------------------------------------
#define FT_S 72
__global__ __launch_bounds__(256, 4) void gram_k(
    const float* __restrict__ F, float* __restrict__ S) {
  const size_t base = ((size_t)blockIdx.y * CCH + blockIdx.x) * HW;
  const float* Fc = F + base;
  float* Sc = S + base;

  __shared__ float Fs[64][68];
  __shared__ unsigned short FtH[64 * FT_S];
  __shared__ unsigned short FtL[64 * FT_S];

  const int tid = threadIdx.x;

  {
    const int h = tid >> 2;
    const int w0 = (tid & 3) * 16;
    const float* src = &Fc[h * 64 + w0];
    float4 v0 = *(const float4*)(src + 0);
    float4 v1 = *(const float4*)(src + 4);
    float4 v2 = *(const float4*)(src + 8);
    float4 v3 = *(const float4*)(src + 12);
    *(float4*)&Fs[h][w0 + 0]  = v0;
    *(float4*)&Fs[h][w0 + 4]  = v1;
    *(float4*)&Fs[h][w0 + 8]  = v2;
    *(float4*)&Fs[h][w0 + 12] = v3;
  }
  __syncthreads();

  {
    const int w = tid & 63;
    const int hc = (tid >> 6) * 16;
    unsigned short hb[16], lb[16];
#pragma unroll
    for (int k = 0; k < 16; ++k) {
      const float x = Fs[hc + k][w];
      const unsigned short h = f2bf(x);
      hb[k] = h;
      lb[k] = f2bf(x - bf2f(h));
    }
    unsigned short* dh = &FtH[w * FT_S + hc];
    unsigned short* dl = &FtL[w * FT_S + hc];
    *(uint4*)(dh + 0) = *(uint4*)&hb[0];
    *(uint4*)(dh + 8) = *(uint4*)&hb[8];
    *(uint4*)(dl + 0) = *(uint4*)&lb[0];
    *(uint4*)(dl + 8) = *(uint4*)&lb[8];
  }
  __syncthreads();

  const int wave = tid >> 6, lane = tid & 63;
  const int wm = (wave >> 1) * 32, wn = (wave & 1) * 32;
  const int fr = lane & 15, kq = (lane >> 4) * 8;

  f32x4 acc[2][2] = {};
#pragma unroll
  for (int kcc = 0; kcc < 2; ++kcc) {
    bf16x8 ah[2], al[2], bh[2], bl[2];
#pragma unroll
    for (int i = 0; i < 2; ++i) {
      ah[i] = *(const bf16x8*)&FtH[(wm + i * 16 + fr) * FT_S + kcc * 32 + kq];
      al[i] = *(const bf16x8*)&FtL[(wm + i * 16 + fr) * FT_S + kcc * 32 + kq];
      bh[i] = *(const bf16x8*)&FtH[(wn + i * 16 + fr) * FT_S + kcc * 32 + kq];
      bl[i] = *(const bf16x8*)&FtL[(wn + i * 16 + fr) * FT_S + kcc * 32 + kq];
    }
#pragma unroll
    for (int i = 0; i < 2; ++i)
#pragma unroll
      for (int j = 0; j < 2; ++j) {
        acc[i][j] = __builtin_amdgcn_mfma_f32_16x16x32_bf16(ah[i], bh[j], acc[i][j], 0, 0, 0);
        acc[i][j] = __builtin_amdgcn_mfma_f32_16x16x32_bf16(ah[i], bl[j], acc[i][j], 0, 0, 0);
        acc[i][j] = __builtin_amdgcn_mfma_f32_16x16x32_bf16(al[i], bh[j], acc[i][j], 0, 0, 0);
      }
  }

  const int rq = (lane >> 4) * 4;
#pragma unroll
  for (int i = 0; i < 2; ++i)
#pragma unroll
    for (int j = 0; j < 2; ++j) {
      const int n = wn + j * 16 + fr;
#pragma unroll
      for (int r = 0; r < 4; ++r) {
        const int m = wm + i * 16 + rq + r;
        Sc[m * 64 + n] = acc[i][j][r];
      }
    }
}

// ---------------------------------------------------------------------------
// K3: softmax over c (both branches) + hadamard + output.
// 1024 thr/block = 64 c-groups x 16 j-lanes (x4 j). 2 blocks/CU.
// ---------------------------------------------------------------------------
__global__ __launch_bounds__(1024, 8) void softmax_fuse_k(
    const float* __restrict__ S, const float* __restrict__ Fbuf,
    float* __restrict__ Out) {
  const int i = blockIdx.x;   // 0..63
  const int b = blockIdx.y;
  const int tid = threadIdx.x;
  const int jl = (tid & 15) * 4;
  const int g = tid >> 4;     // 0..63 (8 c's each)

  const size_t rowO = (size_t)(b * 2) * CHW + (size_t)i * WDIM;
  const size_t rowS = rowO + CHW;

  float mo[4], lo[4], ms[4], ls[4];
#pragma unroll
  for (int k = 0; k < 4; ++k) { mo[k] = -1e30f; lo[k] = 0.f; ms[k] = -1e30f; ls[k] = 0.f; }

#pragma unroll
  for (int cc = 0; cc < 8; ++cc) {
    const int c = g * 8 + cc;
    const size_t off = (size_t)c * HW + jl;
    float4 xo = *(const float4*)&S[rowO + off];
    float4 xs = *(const float4*)&S[rowS + off];
    float xov[4] = {xo.x, xo.y, xo.z, xo.w};
    float xsv[4] = {xs.x, xs.y, xs.z, xs.w};
#pragma unroll
    for (int k = 0; k < 4; ++k) {
      float nm = fmaxf(mo[k], xov[k]);
      lo[k] = lo[k] * __expf(mo[k] - nm) + __expf(xov[k] - nm);
      mo[k] = nm;
      nm = fmaxf(ms[k], xsv[k]);
      ls[k] = ls[k] * __expf(ms[k] - nm) + __expf(xsv[k] - nm);
      ms[k] = nm;
    }
  }

  __shared__ float sm[2][64][64];
  __shared__ float sl[2][64][64];
  __shared__ float Mf[2][64];
  __shared__ float Li[2][64];

  *(float4*)&sm[0][g][jl] = make_float4(mo[0], mo[1], mo[2], mo[3]);
  *(float4*)&sl[0][g][jl] = make_float4(lo[0], lo[1], lo[2], lo[3]);
  *(float4*)&sm[1][g][jl] = make_float4(ms[0], ms[1], ms[2], ms[3]);
  *(float4*)&sl[1][g][jl] = make_float4(ls[0], ls[1], ls[2], ls[3]);
  __syncthreads();

  if (tid < 128) {
    const int br = tid >> 6, j = tid & 63;
    float M = -1e30f;
#pragma unroll 16
    for (int t = 0; t < 64; ++t) M = fmaxf(M, sm[br][t][j]);
    float L = 0.f;
#pragma unroll 16
    for (int t = 0; t < 64; ++t) L += sl[br][t][j] * __expf(sm[br][t][j] - M);
    Mf[br][j] = M;
    Li[br][j] = 1.f / L;
  }
  __syncthreads();

  float4 Mo4 = *(const float4*)&Mf[0][jl];
  float4 iLo4 = *(const float4*)&Li[0][jl];
  float4 Ms4 = *(const float4*)&Mf[1][jl];
  float4 iLs4 = *(const float4*)&Li[1][jl];
  float Mov[4] = {Mo4.x, Mo4.y, Mo4.z, Mo4.w};
  float iLov[4] = {iLo4.x, iLo4.y, iLo4.z, iLo4.w};
  float Msv[4] = {Ms4.x, Ms4.y, Ms4.z, Ms4.w};
  float iLsv[4] = {iLs4.x, iLs4.y, iLs4.z, iLs4.w};

#pragma unroll
  for (int cc = 0; cc < 8; ++cc) {
    const int c = g * 8 + cc;
    const size_t off = (size_t)c * HW + jl;
    float4 xo = *(const float4*)&S[rowO + off];
    float4 xs = *(const float4*)&S[rowS + off];
    float4 fo = *(const float4*)&Fbuf[rowO + off];
    float4 fs = *(const float4*)&Fbuf[rowS + off];
    float xov[4] = {xo.x, xo.y, xo.z, xo.w};
    float xsv[4] = {xs.x, xs.y, xs.z, xs.w};
    float fov[4] = {fo.x, fo.y, fo.z, fo.w};
    float fsv[4] = {fs.x, fs.y, fs.z, fs.w};
    float ov[4];
#pragma unroll
    for (int k = 0; k < 4; ++k) {
      const float ho = __expf(xov[k] - Mov[k]) * iLov[k];
      const float hs = __expf(xsv[k] - Msv[k]) * iLsv[k];
      float h2 = ho * hs;
      h2 *= h2;
      ov[k] = fov[k] * fsv[k] * h2;
    }
    *(float4*)&Out[(size_t)b * CHW + (size_t)c * HW + (size_t)i * WDIM + jl] =
        make_float4(ov[0], ov[1], ov[2], ov[3]);
  }
}

// ---------------------------------------------------------------------------
extern "C" void kernel_launch(void* const* d_in, const int* in_sizes, int n_in,
                              void* d_out, int out_size, void* d_ws, size_t ws_size,
                              hipStream_t stream) {
  const float* opt = (const float*)d_in[0];
  const float* sar = (const float*)d_in[1];
  const float* Wo  = (const float*)d_in[2];
  const float* Wsr = (const float*)d_in[3];
  float* out = (float*)d_out;

  // workspace: Whl | F | S
  unsigned short* Whl = (unsigned short*)d_ws;
  const size_t whlElems = 2u * 2u * 262144u;     // 2 MB
  const size_t perBl = 2 * CHW;                  // elems per batch (both br)
  const size_t perBlBytes = perBl * 8;           // F(4) + S(4)
  int bc = (int)((ws_size - whlElems * 2) / perBlBytes);
  if (bc < 1) bc = 1;
  if (bc > NBATCH) bc = NBATCH;
  const int passes = (NBATCH + bc - 1) / bc;
  const int nbp = (NBATCH + passes - 1) / passes;

  float* Fbuf = (float*)(Whl + whlElems);
  float* Sbuf = Fbuf + (size_t)bc * perBl;

  hipLaunchKernelGGL(wsplit_k, dim3(1024, 2), dim3(256), 0, stream, Wo, Wsr, Whl);

  for (int b0 = 0; b0 < NBATCH; b0 += nbp) {
    const int nb = (NBATCH - b0 < nbp) ? (NBATCH - b0) : nbp;

    hipLaunchKernelGGL(mfma_conv_k, dim3(32, 4, nb * 2), dim3(256), 0, stream,
                       Whl, opt, sar, Fbuf, b0);

    hipLaunchKernelGGL(gram_k, dim3(CCH, nb * 2), dim3(256), 0, stream,
                       Fbuf, Sbuf);

    hipLaunchKernelGGL(softmax_fuse_k, dim3(WDIM, nb), dim3(1024), 0, stream,
                       Sbuf, Fbuf, out + (size_t)b0 * CHW);
  }
}